// Round 4
// baseline (760.803 us; speedup 1.0000x reference)
//
#include <hip/hip_runtime.h>
#include <math.h>

#define HDIM 4096
#define NEXP 64
#define NTOK 16384
#define MBLK 32      // tokens per block
#define TT   8       // token tile (acc rows per lane)
#define KC   256     // k-chunk: lane l owns k = 4l..4l+3
#define NCHUNK (HDIM / KC)       // 16
#define NTILE  (MBLK / TT)       // 4
#define NITER  (NTILE * NCHUNK)  // 64
#define CSTRIDE 68

// DPP-add helper: x + dpp_select(x); masked-out rows contribute 0.
template <int CTRL, int RMASK>
__device__ __forceinline__ float dpp_add(float x) {
    int xi = __builtin_bit_cast(int, x);
    int yi = __builtin_amdgcn_update_dpp(0, xi, CTRL, RMASK, 0xF, true);
    return x + __builtin_bit_cast(float, yi);
}

// Fused router. 512 blocks x 512 threads (8 waves; 128 VGPR cap -> 4 waves/SIMD,
// 2 blocks/CU). Wave w owns experts [8w,8w+8); lane l owns k-slice 4l..4l+3.
// Gate fragment g[8] in VGPRs (reloaded per chunk from L2, reused over 8 tokens).
// A double-buffered in LDS (2 x 8 tokens x 256 k = 16 KB), 1 barrier/chunk.
__global__ __launch_bounds__(512, 4) void router_main(
    const float* __restrict__ hidden,
    const float* __restrict__ gate,
    float* __restrict__ out_rw,
    float* __restrict__ out_sel,
    float* __restrict__ psum_g,
    float* __restrict__ cnt_g,
    float* __restrict__ zsum_g)
{
    __shared__ float A_lds[2][TT * KC];       // 2 x 8 KB
    __shared__ float C_lds[MBLK * CSTRIDE];
    __shared__ float rden[MBLK];
    __shared__ unsigned hist[NEXP];

    const int t = threadIdx.x;
    const int lane = t & 63;
    const int wave = __builtin_amdgcn_readfirstlane(t >> 6);
    const int m0 = blockIdx.x * MBLK;

    const float4* __restrict__ A4 = (const float4*)hidden;   // row = 1024 float4
    const float4* __restrict__ G4 = (const float4*)gate;

    // A fragment for iter j: token row m0 + (j>>4)*TT + wave, float4 col (j&15)*64 + lane
    auto a_load = [&](int j) -> float4 {
        return A4[(size_t)(m0 + (j >> 4) * TT + wave) * (HDIM / 4) + (j & 15) * (KC / 4) + lane];
    };

    float acc[TT][8];
#pragma unroll
    for (int tt = 0; tt < TT; ++tt)
#pragma unroll
        for (int e = 0; e < 8; ++e) acc[tt][e] = 0.f;

    // prologue: stage iter 0, prefetch iter 1
    float4 pref = a_load(0);
    *(float4*)&A_lds[0][wave * KC + lane * 4] = pref;
    pref = a_load(1);
    __syncthreads();

    for (int it = 0; it < NITER; ++it) {
        const int cur = it & 1;
        // gate fragment for this chunk (L2-resident after first tile)
        float4 g[8];
#pragma unroll
        for (int e = 0; e < 8; ++e)
            g[e] = G4[(size_t)(wave * 8 + e) * (HDIM / 4) + (it & 15) * (KC / 4) + lane];
        // stage next chunk's A tile into the other buffer
        if (it + 1 < NITER)
            *(float4*)&A_lds[cur ^ 1][wave * KC + lane * 4] = pref;
        // prefetch A for iter+2
        if (it + 2 < NITER)
            pref = a_load(it + 2);
        // compute: per token 1 ds_read_b128 -> 32 FMAs
#pragma unroll
        for (int tt = 0; tt < TT; ++tt) {
            float4 a = *(const float4*)&A_lds[cur][tt * KC + lane * 4];
#pragma unroll
            for (int e = 0; e < 8; ++e) {
                acc[tt][e] = fmaf(a.x, g[e].x, acc[tt][e]);
                acc[tt][e] = fmaf(a.y, g[e].y, acc[tt][e]);
                acc[tt][e] = fmaf(a.z, g[e].z, acc[tt][e]);
                acc[tt][e] = fmaf(a.w, g[e].w, acc[tt][e]);
            }
        }
        // end of tile: cross-lane K-reduction (6 DPP adds -> lanes 48..63), flush
        if ((it & 15) == 15) {
            const int tile = it >> 4;
#pragma unroll
            for (int tt = 0; tt < TT; ++tt)
#pragma unroll
                for (int e = 0; e < 8; ++e) {
                    float x = acc[tt][e];
                    x = dpp_add<0xB1,  0xF>(x);   // quad_perm xor1
                    x = dpp_add<0x4E,  0xF>(x);   // quad_perm xor2
                    x = dpp_add<0x141, 0xF>(x);   // row_half_mirror
                    x = dpp_add<0x140, 0xF>(x);   // row_mirror
                    x = dpp_add<0x142, 0xA>(x);   // bcast15
                    x = dpp_add<0x143, 0xC>(x);   // bcast31
                    acc[tt][e] = x;
                }
            if (lane == 48) {
#pragma unroll
                for (int tt = 0; tt < TT; ++tt) {
                    *(float4*)&C_lds[(tile * TT + tt) * CSTRIDE + wave * 8 + 0] =
                        make_float4(acc[tt][0], acc[tt][1], acc[tt][2], acc[tt][3]);
                    *(float4*)&C_lds[(tile * TT + tt) * CSTRIDE + wave * 8 + 4] =
                        make_float4(acc[tt][4], acc[tt][5], acc[tt][6], acc[tt][7]);
                }
            }
#pragma unroll
            for (int tt = 0; tt < TT; ++tt)
#pragma unroll
                for (int e = 0; e < 8; ++e) acc[tt][e] = 0.f;
        }
        __syncthreads();
    }

    if (t < NEXP) hist[t] = 0u;
    __syncthreads();

    if (wave != 0) return;   // epilogue on wave 0 (lanes 0..31 = tokens)

    float z = 0.f;
    if (lane < MBLK) {
        // top-2 (strict >, ascending e => ties pick lower index, matches jax)
        float v1 = -INFINITY, v2 = -INFINITY;
        int i1 = 0, i2 = 0;
        for (int e = 0; e < NEXP; ++e) {
            float v = C_lds[lane * CSTRIDE + e];
            if (v > v1)      { v2 = v1; i2 = i1; v1 = v; i1 = e; }
            else if (v > v2) { v2 = v;  i2 = e; }
        }
        atomicAdd(&hist[i1], 1u);
        atomicAdd(&hist[i2], 1u);

        float d = 0.f;
        for (int e = 0; e < NEXP; ++e) {
            float ev = expf(C_lds[lane * CSTRIDE + e] - v1);
            C_lds[lane * CSTRIDE + e] = ev;
            d += ev;
        }
        rden[lane] = 1.0f / d;
        float lse = v1 + logf(d);
        z = lse * lse;

        float e2 = expf(v2 - v1);
        float w2 = e2 / (1.f + e2);
        float w1 = 1.f - w2;
        int tok = m0 + lane;
        out_rw[2 * tok + 0] = w1;
        out_rw[2 * tok + 1] = w2;
        out_sel[2 * tok + 0] = (float)i1;
        out_sel[2 * tok + 1] = (float)i2;
    }

#pragma unroll
    for (int off = 32; off > 0; off >>= 1) z += __shfl_down(z, off);
    if (lane == 0) atomicAdd(zsum_g, z);

    // per-expert prob sums over this block's 32 tokens (lane = expert)
    float ps = 0.f;
    for (int m = 0; m < MBLK; ++m)
        ps += C_lds[m * CSTRIDE + lane] * rden[m];
    atomicAdd(&psum_g[lane], ps);
    atomicAdd(&cnt_g[lane], (float)hist[lane]);
}

__global__ void router_final(const float* __restrict__ ws, float* __restrict__ out_loss)
{
    int e = threadIdx.x;  // 64 threads
    const float inv = 1.0f / (float)NTOK;
    float p = (ws[64 + e] * inv) * (ws[e] * inv);
#pragma unroll
    for (int off = 32; off > 0; off >>= 1) p += __shfl_down(p, off);
    if (e == 0)
        out_loss[0] = 0.01f * (64.f * p) + 0.001f * (ws[128] * inv);
}

extern "C" void kernel_launch(void* const* d_in, const int* in_sizes, int n_in,
                              void* d_out, int out_size, void* d_ws, size_t ws_size,
                              hipStream_t stream) {
    const float* hidden = (const float*)d_in[0];   // [4,4096,4096] fp32
    const float* gate   = (const float*)d_in[1];   // [64,4096] fp32
    float* out = (float*)d_out;                    // 65537 floats
    float* ws  = (float*)d_ws;                     // psum[64] | cnt[64] | zsum[1]

    hipMemsetAsync(d_ws, 0, 129 * sizeof(float), stream);
    router_main<<<dim3(NTOK / MBLK), dim3(512), 0, stream>>>(
        hidden, gate,
        out,                 // routing weights
        out + NTOK * 2,      // selected experts (as floats)
        ws, ws + 64, ws + 128);
    router_final<<<dim3(1), dim3(64), 0, stream>>>(ws, out + NTOK * 4);
}

// Round 5
// 532.372 us; speedup vs baseline: 1.4291x; 1.4291x over previous
//
#include <hip/hip_runtime.h>
#include <math.h>

#define HDIM 4096
#define NEXP 64
#define NTOK 16384
#define MBLK 32      // tokens per block
#define TT   8       // token tile (acc rows per lane)
#define KC   256     // k-chunk: lane l owns k = 4l..4l+3
#define NCHUNK (HDIM / KC)       // 16
#define NTILE  (MBLK / TT)       // 4
#define NITER  (NTILE * NCHUNK)  // 64
#define CSTRIDE 68

// DPP-add helper: x + dpp_select(x); masked-out rows contribute 0.
template <int CTRL, int RMASK>
__device__ __forceinline__ float dpp_add(float x) {
    int xi = __builtin_bit_cast(int, x);
    int yi = __builtin_amdgcn_update_dpp(0, xi, CTRL, RMASK, 0xF, true);
    return x + __builtin_bit_cast(float, yi);
}

// Fused router. 512 blocks x 512 threads.
// NOTE launch_bounds calibration (R3/R4 evidence): 2nd arg acts like CUDA
// min-blocks/CU on this toolchain: (512,2) -> 128-VGPR cap (4 waves/SIMD),
// (512,4) -> 64-VGPR cap (spilled acc to scratch, 715 MB writes, 1.7x slower).
// Register demand here ~118: acc 64 + g 32 + pref 4 + a 4 + addr/misc.
__global__ __launch_bounds__(512, 2) void router_main(
    const float* __restrict__ hidden,
    const float* __restrict__ gate,
    float* __restrict__ out_rw,
    float* __restrict__ out_sel,
    float* __restrict__ psum_g,
    float* __restrict__ cnt_g,
    float* __restrict__ zsum_g)
{
    __shared__ float A_lds[2][TT * KC];       // 2 x 8 KB
    __shared__ float C_lds[MBLK * CSTRIDE];
    __shared__ float rden[MBLK];
    __shared__ unsigned hist[NEXP];

    const int t = threadIdx.x;
    const int lane = t & 63;
    const int wave = __builtin_amdgcn_readfirstlane(t >> 6);
    const int m0 = blockIdx.x * MBLK;

    const float4* __restrict__ A4 = (const float4*)hidden;   // row = 1024 float4
    const float4* __restrict__ G4 = (const float4*)gate;

    // A fragment for iter j: token row m0 + (j>>4)*TT + wave, float4 col (j&15)*64 + lane
    auto a_load = [&](int j) -> float4 {
        return A4[(size_t)(m0 + (j >> 4) * TT + wave) * (HDIM / 4) + (j & 15) * (KC / 4) + lane];
    };

    float acc[TT][8];
#pragma unroll
    for (int tt = 0; tt < TT; ++tt)
#pragma unroll
        for (int e = 0; e < 8; ++e) acc[tt][e] = 0.f;

    // prologue: stage iter 0, prefetch iter 1
    float4 pref = a_load(0);
    *(float4*)&A_lds[0][wave * KC + lane * 4] = pref;
    pref = a_load(1);
    __syncthreads();

    for (int it = 0; it < NITER; ++it) {
        const int cur = it & 1;
        // gate fragment for this chunk (L2-resident after first pass)
        float4 g[8];
#pragma unroll
        for (int e = 0; e < 8; ++e)
            g[e] = G4[(size_t)(wave * 8 + e) * (HDIM / 4) + (it & 15) * (KC / 4) + lane];
        // stage next chunk's A tile into the other buffer
        if (it + 1 < NITER)
            *(float4*)&A_lds[cur ^ 1][wave * KC + lane * 4] = pref;
        // prefetch A for iter+2
        if (it + 2 < NITER)
            pref = a_load(it + 2);
        // compute: per token 1 ds_read_b128 -> 32 FMAs
#pragma unroll
        for (int tt = 0; tt < TT; ++tt) {
            float4 a = *(const float4*)&A_lds[cur][tt * KC + lane * 4];
#pragma unroll
            for (int e = 0; e < 8; ++e) {
                acc[tt][e] = fmaf(a.x, g[e].x, acc[tt][e]);
                acc[tt][e] = fmaf(a.y, g[e].y, acc[tt][e]);
                acc[tt][e] = fmaf(a.z, g[e].z, acc[tt][e]);
                acc[tt][e] = fmaf(a.w, g[e].w, acc[tt][e]);
            }
        }
        // end of tile: cross-lane K-reduction (6 DPP adds -> lanes 48..63), flush
        if ((it & 15) == 15) {
            const int tile = it >> 4;
#pragma unroll
            for (int tt = 0; tt < TT; ++tt)
#pragma unroll
                for (int e = 0; e < 8; ++e) {
                    float x = acc[tt][e];
                    x = dpp_add<0xB1,  0xF>(x);   // quad_perm xor1
                    x = dpp_add<0x4E,  0xF>(x);   // quad_perm xor2
                    x = dpp_add<0x141, 0xF>(x);   // row_half_mirror
                    x = dpp_add<0x140, 0xF>(x);   // row_mirror
                    x = dpp_add<0x142, 0xA>(x);   // bcast15
                    x = dpp_add<0x143, 0xC>(x);   // bcast31
                    acc[tt][e] = x;
                }
            if (lane == 48) {
#pragma unroll
                for (int tt = 0; tt < TT; ++tt) {
                    *(float4*)&C_lds[(tile * TT + tt) * CSTRIDE + wave * 8 + 0] =
                        make_float4(acc[tt][0], acc[tt][1], acc[tt][2], acc[tt][3]);
                    *(float4*)&C_lds[(tile * TT + tt) * CSTRIDE + wave * 8 + 4] =
                        make_float4(acc[tt][4], acc[tt][5], acc[tt][6], acc[tt][7]);
                }
            }
#pragma unroll
            for (int tt = 0; tt < TT; ++tt)
#pragma unroll
                for (int e = 0; e < 8; ++e) acc[tt][e] = 0.f;
        }
        __syncthreads();
    }

    if (t < NEXP) hist[t] = 0u;
    __syncthreads();

    if (wave != 0) return;   // epilogue on wave 0 (lanes 0..31 = tokens)

    float z = 0.f;
    if (lane < MBLK) {
        // top-2 (strict >, ascending e => ties pick lower index, matches jax)
        float v1 = -INFINITY, v2 = -INFINITY;
        int i1 = 0, i2 = 0;
        for (int e = 0; e < NEXP; ++e) {
            float v = C_lds[lane * CSTRIDE + e];
            if (v > v1)      { v2 = v1; i2 = i1; v1 = v; i1 = e; }
            else if (v > v2) { v2 = v;  i2 = e; }
        }
        atomicAdd(&hist[i1], 1u);
        atomicAdd(&hist[i2], 1u);

        float d = 0.f;
        for (int e = 0; e < NEXP; ++e) {
            float ev = expf(C_lds[lane * CSTRIDE + e] - v1);
            C_lds[lane * CSTRIDE + e] = ev;
            d += ev;
        }
        rden[lane] = 1.0f / d;
        float lse = v1 + logf(d);
        z = lse * lse;

        float e2 = expf(v2 - v1);
        float w2 = e2 / (1.f + e2);
        float w1 = 1.f - w2;
        int tok = m0 + lane;
        out_rw[2 * tok + 0] = w1;
        out_rw[2 * tok + 1] = w2;
        out_sel[2 * tok + 0] = (float)i1;
        out_sel[2 * tok + 1] = (float)i2;
    }

#pragma unroll
    for (int off = 32; off > 0; off >>= 1) z += __shfl_down(z, off);
    if (lane == 0) atomicAdd(zsum_g, z);

    // per-expert prob sums over this block's 32 tokens (lane = expert)
    float ps = 0.f;
    for (int m = 0; m < MBLK; ++m)
        ps += C_lds[m * CSTRIDE + lane] * rden[m];
    atomicAdd(&psum_g[lane], ps);
    atomicAdd(&cnt_g[lane], (float)hist[lane]);
}

__global__ void router_final(const float* __restrict__ ws, float* __restrict__ out_loss)
{
    int e = threadIdx.x;  // 64 threads
    const float inv = 1.0f / (float)NTOK;
    float p = (ws[64 + e] * inv) * (ws[e] * inv);
#pragma unroll
    for (int off = 32; off > 0; off >>= 1) p += __shfl_down(p, off);
    if (e == 0)
        out_loss[0] = 0.01f * (64.f * p) + 0.001f * (ws[128] * inv);
}

extern "C" void kernel_launch(void* const* d_in, const int* in_sizes, int n_in,
                              void* d_out, int out_size, void* d_ws, size_t ws_size,
                              hipStream_t stream) {
    const float* hidden = (const float*)d_in[0];   // [4,4096,4096] fp32
    const float* gate   = (const float*)d_in[1];   // [64,4096] fp32
    float* out = (float*)d_out;                    // 65537 floats
    float* ws  = (float*)d_ws;                     // psum[64] | cnt[64] | zsum[1]

    hipMemsetAsync(d_ws, 0, 129 * sizeof(float), stream);
    router_main<<<dim3(NTOK / MBLK), dim3(512), 0, stream>>>(
        hidden, gate,
        out,                 // routing weights
        out + NTOK * 2,      // selected experts (as floats)
        ws, ws + 64, ws + 128);
    router_final<<<dim3(1), dim3(64), 0, stream>>>(ws, out + NTOK * 4);
}